// Round 5
// baseline (34.438 us; speedup 1.0000x reference)
//
#include <hip/hip_runtime.h>

// Fully-fused 4-level db4 wavedec ('symmetric'), b128-window version.
// x: [B=64, L=4096, C=32] f32. Out flat: cA4,cD4,cD3,cD2,cD1 each [B,C,len].
// lens: 4096 -> 2051 -> 1029 -> 518 -> 262.
// Block = (batch, 4-ch group, tile of up-to-34 cA4 outputs); 4096 blocks x 256.
// Even tile partition (lo4=34t) keeps every run start even => aligned b128
// window loads; per-channel mod-4 phase shift on cd staging => float4 dumps.

#define NT 256
#define NCHB 4

// LDS row pitches (floats); all == 0 mod 4; c*P mod 32 distinct (P mod 32 != 0,16).
#define LPX 644
#define LP1 324
#define LP2 164
#define LP3 84
#define CDPA 320
#define CDPB 164
#define CAP4 40

#define L0C 4096
#define L1C 2051
#define L2C 1029
#define L3C 518
#define L4C 262
#define SC 2048

#define OFF_CD4 (SC * L4C)
#define OFF_CD3 (2 * SC * L4C)
#define OFF_CD2 (OFF_CD3 + SC * L3C)
#define OFF_CD1 (OFF_CD2 + SC * L2C)

__device__ __forceinline__ void filt8(const float* w, float& a, float& d) {
    // db4 correlation kernels (dec_lo reversed = _H; dec_hi reversed), 2 chains each.
    constexpr float FLO[8] = {
        0.23037781330885523f,  0.7148465705525415f,  0.6308807679295904f,
        -0.02798376941698385f, -0.18703481171888114f, 0.030841381835986965f,
        0.032883011666982945f, -0.010597401784997278f};
    constexpr float FHI[8] = {
        -0.010597401784997278f, -0.032883011666982945f, 0.030841381835986965f,
        0.18703481171888114f,  -0.02798376941698385f,  -0.6308807679295904f,
        0.7148465705525415f,   -0.23037781330885523f};
    float a0 = FLO[0] * w[0];
    a0 = fmaf(FLO[1], w[1], a0); a0 = fmaf(FLO[2], w[2], a0); a0 = fmaf(FLO[3], w[3], a0);
    float a1 = FLO[4] * w[4];
    a1 = fmaf(FLO[5], w[5], a1); a1 = fmaf(FLO[6], w[6], a1); a1 = fmaf(FLO[7], w[7], a1);
    a = a0 + a1;
    float d0 = FHI[0] * w[0];
    d0 = fmaf(FHI[1], w[1], d0); d0 = fmaf(FHI[2], w[2], d0); d0 = fmaf(FHI[3], w[3], d0);
    float d1 = FHI[4] * w[4];
    d1 = fmaf(FHI[5], w[5], d1); d1 = fmaf(FHI[6], w[6], d1); d1 = fmaf(FHI[7], w[7], d1);
    d = d0 + d1;
}

// One level for one thread: R consecutive outputs for channel c, b128 window.
// rowbase: src row (src + c*PS); sample t stored at word t - srclo + spad.
// drowA[i] = a (next-level row, word i - dstlo + dpad; pointer pre-shifted).
// cdrow[i] = d (staging, pre-shifted). carow[i] = a for LAST.
template <int R, bool MG, bool LAST>
__device__ __forceinline__ void level_run(
    const float* __restrict__ rowbase, int srclo, int spad,
    float* __restrict__ drowA, int DL,
    float* __restrict__ cdrow, float* __restrict__ carow,
    int lo, int hi, int slot) {
    constexpr int NW = 2 * R + 6;
    constexpr int NQ = (NW + 3) / 4;
    const int span = hi - lo;
    int i0r = slot * R;
    const int cap = (span - R) & ~1;  // even clamp keeps b128 alignment
    if (i0r > cap) i0r = cap;
    const int i0 = lo + i0r;

    const float4* rq = reinterpret_cast<const float4*>(rowbase + (2 * i0 - 6 - srclo + spad));
    float w[NQ * 4];
#pragma unroll
    for (int j = 0; j < NQ; ++j) {
        const float4 t4 = rq[j];
        w[4 * j + 0] = t4.x; w[4 * j + 1] = t4.y;
        w[4 * j + 2] = t4.z; w[4 * j + 3] = t4.w;
    }
    float av[R], dv[R];
#pragma unroll
    for (int r = 0; r < R; ++r) filt8(&w[2 * r], av[r], dv[r]);

    if constexpr (!LAST) {
        float2* dp2 = reinterpret_cast<float2*>(drowA + i0);
#pragma unroll
        for (int m = 0; m < R / 2; ++m) dp2[m] = make_float2(av[2 * m], av[2 * m + 1]);
        if constexpr (MG) {
#pragma unroll
            for (int r = 0; r < R; ++r) {
                const int i = i0 + r;
                if (i < 6) drowA[-1 - i] = av[r];                      // left reflection
                if (i >= DL - 7) drowA[2 * DL - 1 - i] = av[r];        // right reflection
            }
        }
    } else {
#pragma unroll
        for (int r = 0; r < R; ++r) carow[i0 + r] = av[r];
    }
#pragma unroll
    for (int r = 0; r < R; ++r) cdrow[i0 + r] = dv[r];

    // odd (span-R): output hi-1 uncovered by even-clamped runs -> b64 fixup
    if (((span - R) & 1) && slot == 0) {
        const int i = hi - 1;
        const float2* r2 = reinterpret_cast<const float2*>(rowbase + (2 * i - 6 - srclo + spad));
        float ww[8];
#pragma unroll
        for (int j = 0; j < 4; ++j) { const float2 t2 = r2[j]; ww[2 * j] = t2.x; ww[2 * j + 1] = t2.y; }
        float a, d;
        filt8(ww, a, d);
        if constexpr (!LAST) {
            drowA[i] = a;
            if constexpr (MG) { if (i >= DL - 7) drowA[2 * DL - 1 - i] = a; }
        } else {
            carow[i] = a;
        }
        cdrow[i] = d;
    }
}

// Dump staged rows to global, float4 middle + scalar head/tail (<=3 each).
// Staging word = c2*CDP + (i - lo) + ((g + lo) & 3)  ==  g + i (mod 4).
__device__ __forceinline__ void dump_seg(
    const float* __restrict__ buf, int CDP, int lo, int Len,
    float* __restrict__ gchunk, int ownLo, int ownHi, int sigB, int tid) {
#pragma unroll
    for (int c2 = 0; c2 < NCHB; ++c2) {
        const int g = (sigB + c2) * Len;
        const int padc = (g + lo) & 3;
        const float* srow = buf + c2 * CDP + padc - lo;
        float* grow = gchunk + g;
        const int a0 = ownLo + ((4 - ((g + ownLo) & 3)) & 3);
        const int a1 = ownHi - ((g + ownHi) & 3);
        if (tid < a0 - ownLo) grow[ownLo + tid] = srow[ownLo + tid];
        const int ntail = ownHi - a1;
        if (tid >= 8 && tid < 8 + ntail) grow[a1 + tid - 8] = srow[a1 + tid - 8];
        const int n4 = (a1 - a0) >> 2;
        for (int k = tid; k < n4; k += NT) {
            const int i = a0 + 4 * k;
            *reinterpret_cast<float4*>(grow + i) = *reinterpret_cast<const float4*>(srow + i);
        }
    }
}

template <bool MG>
__device__ __forceinline__ void run_cascade(
    float* bx, float* b1, float* b2, float* b3,
    float* cdA, float* cdB, float* caB,
    float* __restrict__ out, int sigB, int tile, int c, int slot, int tid,
    int lox, int lo1, int hi1, int lo2, int hi2, int lo3, int hi3, int lo4, int hi4) {
    const int xpad = 6 + (lox & 3);
    const int p1 = 6 + (lo1 & 3);
    const int p2 = 6 + (lo2 & 3);
    const int p3 = 6 + (lo3 & 3);

    // owned (exclusive, tile-consistent) detail ranges
    const int o1lo = tile ? 272 * tile - 34 : 0;
    const int o1hi = (tile == 7) ? L1C : 272 * tile + 238;
    const int o2lo = tile ? 136 * tile - 10 : 0;
    const int o2hi = (tile == 7) ? L2C : 136 * tile + 126;
    const int o3lo = tile ? 68 * tile - 2 : 0;
    const int o3hi = (tile == 7) ? L3C : 68 * tile + 66;

    {   // level 1: x -> b1, cd1 -> cdA
        float* drow = b1 + c * LP1 + p1 - lo1;
        float* cdrow = cdA + c * CDPA + (((sigB + c) * L1C + lo1) & 3) - lo1;
        level_run<6, MG, false>(bx + c * LPX, lox, xpad, drow, L1C, cdrow, nullptr, lo1, hi1, slot);
    }
    __syncthreads();

    dump_seg(cdA, CDPA, lo1, L1C, out + OFF_CD1, o1lo, o1hi, sigB, tid);
    {   // level 2: b1 -> b2, cd2 -> cdB
        float* drow = b2 + c * LP2 + p2 - lo2;
        float* cdrow = cdB + c * CDPB + (((sigB + c) * L2C + lo2) & 3) - lo2;
        level_run<4, MG, false>(b1 + c * LP1, lo1, p1, drow, L2C, cdrow, nullptr, lo2, hi2, slot);
    }
    __syncthreads();

    dump_seg(cdB, CDPB, lo2, L2C, out + OFF_CD2, o2lo, o2hi, sigB, tid);
    {   // level 3: b2 -> b3, cd3 -> cdA (reuse)
        float* drow = b3 + c * LP3 + p3 - lo3;
        float* cdrow = cdA + c * CDPA + (((sigB + c) * L3C + lo3) & 3) - lo3;
        level_run<2, MG, false>(b2 + c * LP2, lo2, p2, drow, L3C, cdrow, nullptr, lo3, hi3, slot);
    }
    __syncthreads();

    dump_seg(cdA, CDPA, lo3, L3C, out + OFF_CD3, o3lo, o3hi, sigB, tid);
    {   // level 4: b3 -> cd4 (cdB), ca4 (caB)
        float* cdrow = cdB + c * CDPB + (((sigB + c) * L4C + lo4) & 3) - lo4;
        float* carow = caB + c * CAP4 + (((sigB + c) * L4C + lo4) & 3) - lo4;
        level_run<2, MG, true>(b3 + c * LP3, lo3, p3, nullptr, L4C, cdrow, carow, lo4, hi4, slot);
    }
    __syncthreads();

    dump_seg(cdB, CDPB, lo4, L4C, out + OFF_CD4, lo4, hi4, sigB, tid);
    dump_seg(caB, CAP4, lo4, L4C, out, lo4, hi4, sigB, tid);
}

__global__ __launch_bounds__(NT, 5) void fused_dwt_kernel(
    const float* __restrict__ x, float* __restrict__ out) {
    __shared__ __align__(16) float bx[NCHB * LPX];
    __shared__ __align__(16) float b1[NCHB * LP1];
    __shared__ __align__(16) float b2[NCHB * LP2];
    __shared__ __align__(16) float b3[NCHB * LP3];
    __shared__ __align__(16) float cdA[NCHB * CDPA];
    __shared__ __align__(16) float cdB[NCHB * CDPB];
    __shared__ __align__(16) float caB[NCHB * CAP4];

    // XCD swizzle: 4096 blocks = 8 XCDs x 512 contiguous works, so the 8
    // channel-group siblings (consecutive works) share one XCD's L2.
    const int bid = blockIdx.x;
    const int work = (bid & 7) * 512 + (bid >> 3);
    const int cg = work & 7;           // channel group 0..7 (4 ch each)
    const int tile = (work >> 3) & 7;  // cA4 tile 0..7
    const int b = work >> 6;           // batch 0..63

    const int tid = threadIdx.x;
    const int c = tid & 3;
    const int slot = tid >> 2;  // 0..63
    const int c0 = cg * 4;
    const int sigB = b * 32 + c0;

    // even tile partition (lo4 = 34t) => all level los even
    const int lo4 = 34 * tile, hi4 = min(L4C, lo4 + 34);
    const int lo3 = max(0, 2 * lo4 - 6), hi3 = min(L3C, 2 * hi4);
    const int lo2 = max(0, 2 * lo3 - 6), hi2 = min(L2C, 2 * hi3);
    const int lo1 = max(0, 2 * lo2 - 6), hi1 = min(L1C, 2 * hi2);
    const int lox = max(0, 2 * lo1 - 6), hix = min(L0C, 2 * hi1);

    // ---- stage x tile into transposed rows, b64 pair writes (+ reflections) ----
    const int xpad = 6 + (lox & 3);
    const float* xb = x + (size_t)b * (L0C * 32) + c0;
    const int npair = (hix - lox) >> 1;
    for (int q = tid; q < npair; q += NT) {
        const int j = q << 1;
        const int t = lox + j;
        const float4 va = *reinterpret_cast<const float4*>(xb + (size_t)t * 32);
        const float4 vb = *reinterpret_cast<const float4*>(xb + (size_t)(t + 1) * 32);
        const float avv[4] = {va.x, va.y, va.z, va.w};
        const float bvv[4] = {vb.x, vb.y, vb.z, vb.w};
#pragma unroll
        for (int hh = 0; hh < 4; ++hh)
            *reinterpret_cast<float2*>(bx + hh * LPX + xpad + j) = make_float2(avv[hh], bvv[hh]);
        if (lox == 0 && t < 6) {
#pragma unroll
            for (int hh = 0; hh < 4; ++hh) {
                bx[hh * LPX + xpad - 1 - t] = avv[hh];
                if (t + 1 < 6) bx[hh * LPX + xpad - 2 - t] = bvv[hh];
            }
        }
        if (hix == L0C && t + 1 >= L0C - 7) {
#pragma unroll
            for (int hh = 0; hh < 4; ++hh) {
                if (t >= L0C - 7) bx[hh * LPX + (2 * L0C - 1 - t) - lox + xpad] = avv[hh];
                bx[hh * LPX + (2 * L0C - 2 - t) - lox + xpad] = bvv[hh];
            }
        }
    }
    __syncthreads();

    if (tile == 0 || tile == 7)
        run_cascade<true>(bx, b1, b2, b3, cdA, cdB, caB, out, sigB, tile, c, slot, tid,
                          lox, lo1, hi1, lo2, hi2, lo3, hi3, lo4, hi4);
    else
        run_cascade<false>(bx, b1, b2, b3, cdA, cdB, caB, out, sigB, tile, c, slot, tid,
                           lox, lo1, hi1, lo2, hi2, lo3, hi3, lo4, hi4);
}

extern "C" void kernel_launch(void* const* d_in, const int* in_sizes, int n_in,
                              void* d_out, int out_size, void* d_ws, size_t ws_size,
                              hipStream_t stream) {
    (void)in_sizes; (void)n_in; (void)d_ws; (void)ws_size; (void)out_size;
    const float* x = (const float*)d_in[0];
    float* out = (float*)d_out;
    fused_dwt_kernel<<<dim3(4096), dim3(NT), 0, stream>>>(x, out);
}

// Round 6
// 32.876 us; speedup vs baseline: 1.0475x; 1.0475x over previous
//
#include <hip/hip_runtime.h>

// Fully-fused 4-level db4 wavedec ('symmetric'), faithful to the JAX/pywt reference.
// x: [B=64, L=4096, C=32] f32. Out flat: cA4,cD4,cD3,cD2,cD1 each [B,C,len].
// lens: 4096 -> 2051 -> 1029 -> 518 -> 262.
// Block = (batch, 2-ch group, tile of 33 cA4 outputs); 8192 blocks x 256 thr.
// 13.7 KB LDS -> 8 blocks/CU (32 waves, 100% occupancy cap). Compute: register
// sliding window over transposed per-channel LDS rows (b64 reads, bank-uniform);
// all global writes staged in LDS and dumped coalesced, overlapped w/ next level.

#define NT 256
#define NCHB 2

// Row pitches (floats): pitch mod 4 == 2 => b64 window starts spread uniformly
// (4 lanes per bank-pair = wave64 minimum) for R=3/2/1.
#define LPX 634  // x span <= 618 (+13 margins)
#define LP1 322  // l1 span <= 306
#define LP2 166  // l2 span <= 150
#define LP3 86   // l3 span <= 72
#define CDPA 314 // cd staging for L1/L3
#define CDPB 154 // cd staging for L2/L4
#define CAP4 40  // cA4 staging

#define L0C 4096
#define L1C 2051
#define L2C 1029
#define L3C 518
#define L4C 262
#define SC 2048

#define OFF_CD4 (SC * L4C)
#define OFF_CD3 (2 * SC * L4C)
#define OFF_CD2 (OFF_CD3 + SC * L3C)
#define OFF_CD1 (OFF_CD2 + SC * L2C)

__device__ __forceinline__ void filt8(
    const float w0, const float w1, const float w2, const float w3,
    const float w4, const float w5, const float w6, const float w7,
    float& a, float& d) {
    // db4 correlation kernels (dec_lo reversed = _H; dec_hi reversed), split trees.
    constexpr float FLO[8] = {
        0.23037781330885523f,  0.7148465705525415f,  0.6308807679295904f,
        -0.02798376941698385f, -0.18703481171888114f, 0.030841381835986965f,
        0.032883011666982945f, -0.010597401784997278f};
    constexpr float FHI[8] = {
        -0.010597401784997278f, -0.032883011666982945f, 0.030841381835986965f,
        0.18703481171888114f,  -0.02798376941698385f,  -0.6308807679295904f,
        0.7148465705525415f,   -0.23037781330885523f};
    float a0 = FLO[0] * w0;
    a0 = fmaf(FLO[1], w1, a0); a0 = fmaf(FLO[2], w2, a0); a0 = fmaf(FLO[3], w3, a0);
    float a1 = FLO[4] * w4;
    a1 = fmaf(FLO[5], w5, a1); a1 = fmaf(FLO[6], w6, a1); a1 = fmaf(FLO[7], w7, a1);
    a = a0 + a1;
    float d0 = FHI[0] * w0;
    d0 = fmaf(FHI[1], w1, d0); d0 = fmaf(FHI[2], w2, d0); d0 = fmaf(FHI[3], w3, d0);
    float d1 = FHI[4] * w4;
    d1 = fmaf(FHI[5], w5, d1); d1 = fmaf(FHI[6], w6, d1); d1 = fmaf(FHI[7], w7, d1);
    d = d0 + d1;
}

template <int R, bool LAST>
__device__ __forceinline__ void level_run(
    const float* __restrict__ src, int PS, int srclo,
    float* __restrict__ dst, int PD, int DL,
    int lo, int hi,
    float* __restrict__ cdbuf, int CDP,
    float* __restrict__ cabuf,
    int c, int slot) {
    const int span = hi - lo;
    int i0r = slot * R;
    if (i0r > span - R) i0r = span - R;  // clamp (duplicates idempotent)
    const int i0 = lo + i0r;

    const float2* row2 = reinterpret_cast<const float2*>(src + c * PS);
    int p = i0 - (srclo >> 1);  // sample t at word t-srclo+6; first tap t=2i-6
    float2 f0 = row2[p], f1 = row2[p + 1], f2 = row2[p + 2];
    float* drow = LAST ? nullptr : dst + c * PD;
    float* cdrow = cdbuf + c * CDP - lo;
    float* carow = LAST ? cabuf + c * CAP4 - lo : nullptr;

#pragma unroll
    for (int r = 0; r < R; ++r) {
        const float2 f3 = row2[p + 3 + r];
        const int i = i0 + r;
        float a, d;
        filt8(f0.x, f0.y, f1.x, f1.y, f2.x, f2.y, f3.x, f3.y, a, d);

        if constexpr (!LAST) {
            drow[i - lo + 6] = a;
            // reflection margins for next level (boundary tiles only)
            if (lo == 0 && i < 6) drow[5 - i] = a;
            if (hi == DL && i >= DL - 7) drow[(2 * DL - 1 - i) - lo + 6] = a;
        } else {
            carow[i] = a;
        }
        cdrow[i] = d;
        f0 = f1; f1 = f2; f2 = f3;
    }
}

__device__ __forceinline__ void dump_rows(
    const float* __restrict__ buf, int pitch, int bufLo,
    float* __restrict__ gbase, int rowLen, int ownLo, int ownHi, int tid) {
    const int span = ownHi - ownLo;
#pragma unroll
    for (int c2 = 0; c2 < NCHB; ++c2) {
        float* g = gbase + (size_t)c2 * rowLen + ownLo;
        const float* s = buf + c2 * pitch + (ownLo - bufLo);
        for (int i = tid; i < span; i += NT) g[i] = s[i];
    }
}

__global__ __launch_bounds__(NT, 8) void fused_dwt_kernel(
    const float* __restrict__ x, float* __restrict__ out) {
    __shared__ __align__(16) float bx[NCHB * LPX];
    __shared__ __align__(16) float b1[NCHB * LP1];
    __shared__ __align__(16) float b2[NCHB * LP2];
    __shared__ __align__(16) float b3[NCHB * LP3];
    __shared__ __align__(16) float cdA[NCHB * CDPA];
    __shared__ __align__(16) float cdB[NCHB * CDPB];
    __shared__ __align__(16) float caB[NCHB * CAP4];

    // XCD swizzle: 8192 blocks = 8 XCDs x 1024 contiguous works; the 16
    // channel-group siblings (consecutive works) share one XCD's L2.
    const int bid = blockIdx.x;
    const int work = (bid & 7) * 1024 + (bid >> 3);
    const int cg = work & 15;          // channel group 0..15 (2 ch each)
    const int tile = (work >> 4) & 7;  // cA4 tile 0..7
    const int b = work >> 7;           // batch 0..63

    const int tid = threadIdx.x;
    const int c = tid & 1;
    const int slot = tid >> 1;  // 0..127
    const int c0 = cg * 2;
    const int sigB = b * 32 + c0;

    const int lo4 = 33 * tile, hi4 = min(L4C, lo4 + 33);
    const int lo3 = max(0, 2 * lo4 - 6), hi3 = min(L3C, 2 * hi4);
    const int lo2 = max(0, 2 * lo3 - 6), hi2 = min(L2C, 2 * hi3);
    const int lo1 = max(0, 2 * lo2 - 6), hi1 = min(L1C, 2 * hi2);
    const int lox = max(0, 2 * lo1 - 6), hix = min(L0C, 2 * hi1);

    // ---- stage x tile into transposed rows, float2 pair writes (+ reflections) ----
    const float* xb = x + (size_t)b * (L0C * 32) + c0;
    const int npair = (hix - lox) >> 1;
    for (int q = tid; q < npair; q += NT) {
        const int j = q << 1;
        const int t = lox + j;
        const float2 va = *reinterpret_cast<const float2*>(xb + (size_t)t * 32);
        const float2 vb = *reinterpret_cast<const float2*>(xb + (size_t)(t + 1) * 32);
        const float avv[2] = {va.x, va.y};
        const float bvv[2] = {vb.x, vb.y};
#pragma unroll
        for (int hh = 0; hh < NCHB; ++hh)
            *reinterpret_cast<float2*>(bx + hh * LPX + 6 + j) = make_float2(avv[hh], bvv[hh]);
        if (lox == 0 && t < 6) {
#pragma unroll
            for (int hh = 0; hh < NCHB; ++hh) {
                bx[hh * LPX + 5 - t] = avv[hh];
                if (t + 1 < 6) bx[hh * LPX + 4 - t] = bvv[hh];
            }
        }
        if (hix == L0C && t + 1 >= L0C - 7) {
#pragma unroll
            for (int hh = 0; hh < NCHB; ++hh) {
                if (t >= L0C - 7) bx[hh * LPX + (2 * L0C - 1 - t) - lox + 6] = avv[hh];
                bx[hh * LPX + (2 * L0C - 2 - t) - lox + 6] = bvv[hh];
            }
        }
    }
    __syncthreads();

    // d_out chunk bases for this block's channels
    float* gca4 = out + (size_t)sigB * L4C;
    float* gcd4 = out + OFF_CD4 + (size_t)sigB * L4C;
    float* gcd3 = out + OFF_CD3 + (size_t)sigB * L3C;
    float* gcd2 = out + OFF_CD2 + (size_t)sigB * L2C;
    float* gcd1 = out + OFF_CD1 + (size_t)sigB * L1C;

    // owned (exclusive, tile-partitioned) detail ranges
    const int o1lo = tile ? 264 * tile - 34 : 0;
    const int o1hi = (tile == 7) ? L1C : 264 * tile + 230;
    const int o2lo = tile ? 132 * tile - 10 : 0;
    const int o2hi = (tile == 7) ? L2C : 132 * tile + 122;
    const int o3lo = tile ? 66 * tile - 2 : 0;
    const int o3hi = (tile == 7) ? L3C : 66 * tile + 64;

    level_run<3, false>(bx, LPX, lox, b1, LP1, L1C, lo1, hi1, cdA, CDPA, nullptr, c, slot);
    __syncthreads();

    dump_rows(cdA, CDPA, lo1, gcd1, L1C, o1lo, o1hi, tid);
    level_run<2, false>(b1, LP1, lo1, b2, LP2, L2C, lo2, hi2, cdB, CDPB, nullptr, c, slot);
    __syncthreads();

    dump_rows(cdB, CDPB, lo2, gcd2, L2C, o2lo, o2hi, tid);
    level_run<1, false>(b2, LP2, lo2, b3, LP3, L3C, lo3, hi3, cdA, CDPA, nullptr, c, slot);
    __syncthreads();

    dump_rows(cdA, CDPA, lo3, gcd3, L3C, o3lo, o3hi, tid);
    level_run<1, true>(b3, LP3, lo3, nullptr, 0, L4C, lo4, hi4, cdB, CDPB, caB, c, slot);
    __syncthreads();

    dump_rows(cdB, CDPB, lo4, gcd4, L4C, lo4, hi4, tid);
    dump_rows(caB, CAP4, lo4, gca4, L4C, lo4, hi4, tid);
}

extern "C" void kernel_launch(void* const* d_in, const int* in_sizes, int n_in,
                              void* d_out, int out_size, void* d_ws, size_t ws_size,
                              hipStream_t stream) {
    (void)in_sizes; (void)n_in; (void)d_ws; (void)ws_size; (void)out_size;
    const float* x = (const float*)d_in[0];
    float* out = (float*)d_out;
    fused_dwt_kernel<<<dim3(8192), dim3(NT), 0, stream>>>(x, out);
}